// Round 1
// 99.864 us; speedup vs baseline: 1.0102x; 1.0102x over previous
//
#include <hip/hip_runtime.h>

#define N_NODES 10000
#define N_EDGES 320000
#define KDIM 640            // 5 * 128
#define C_OUT 128

typedef __attribute__((ext_vector_type(8))) short short8;   // 8 bf16
typedef __attribute__((ext_vector_type(4))) float floatx4;  // MFMA C/D + nt loads
typedef __attribute__((ext_vector_type(2))) unsigned int uintx2;

// ---- bf16 helpers ---------------------------------------------------------
__device__ __forceinline__ unsigned short f2bf(float f) {
    unsigned int b = __float_as_uint(f);
    b = (b + 0x7FFFu + ((b >> 16) & 1u)) >> 16;   // RNE
    return (unsigned short)b;
}
__device__ __forceinline__ unsigned int pack2(float x, float y) {
    return (unsigned int)f2bf(x) | ((unsigned int)f2bf(y) << 16);
}
__device__ __forceinline__ float2 unpack2(unsigned int u) {
    float2 r;
    r.x = __uint_as_float(u << 16);
    r.y = __uint_as_float(u & 0xFFFF0000u);
    return r;
}

// ---------------------------------------------------------------------------
// Prep kernel: one launch, three block roles (unchanged from round 9).
//   [0,1250)    : h (f32) -> hb (bf16)   (nt reads; cached writes)
//   [1250,1330) : W -> Wt (128x640 bf16) transposed
//   [1330,1370) : CSR offsets via binary search over sorted src
// ---------------------------------------------------------------------------
__global__ __launch_bounds__(256) void prep(
        const float* __restrict__ h, uintx2* __restrict__ hb4,
        const float* __restrict__ W, unsigned short* __restrict__ Wt,
        const int* __restrict__ src, int* __restrict__ offsets) {
    const int bid = blockIdx.x;
    const int tid = threadIdx.x;

    if (bid < 1250) {                       // conv_h: 1250*256 = 320000 exact
        const int t = bid * 256 + tid;
        floatx4 v = __builtin_nontemporal_load(&((const floatx4*)h)[t]);
        uintx2 o;
        o.x = pack2(v.x, v.y);
        o.y = pack2(v.z, v.w);
        hb4[t] = o;                         // cached: want hb4 L2-resident
    } else if (bid < 1330) {                // conv_w transpose, 80 blocks
        __shared__ float tile[32][33];
        const int b = bid - 1250;
        const int k0 = (b % 20) * 32, o0 = (b / 20) * 32;
        const int tx = tid & 31, ty = tid >> 5;      // 32 x 8
#pragma unroll
        for (int i = 0; i < 4; ++i)
            tile[ty + 8 * i][tx] =
                __builtin_nontemporal_load(&W[(size_t)(k0 + ty + 8 * i) * C_OUT + o0 + tx]);
        __syncthreads();
#pragma unroll
        for (int i = 0; i < 4; ++i)
            Wt[(size_t)(o0 + ty + 8 * i) * KDIM + k0 + tx] = f2bf(tile[tx][ty + 8 * i]);
    } else {                                // offsets, 40 blocks
        const int n = (bid - 1330) * 256 + tid;
        if (n > N_NODES) return;
        int lo = 0, hi = N_EDGES;
        while (lo < hi) {
            int mid = (lo + hi) >> 1;
            if (src[mid] < n) lo = mid + 1; else hi = mid;
        }
        offsets[n] = lo;
    }
}

// ---------------------------------------------------------------------------
// 8-edge FMA block: consume 8 gathered dwords (u) + scalar X rows.
// ---------------------------------------------------------------------------
__device__ __forceinline__ void edge_fma8(const float* __restrict__ X, int e,
                                          const unsigned int* u, float2* a) {
#pragma unroll
    for (int q = 0; q < 8; ++q) {
        const float* Xp = X + (size_t)(e + q) * 5;        // s_loads
        const float x0 = Xp[0], x1 = Xp[1], x2 = Xp[2], x3 = Xp[3], x4 = Xp[4];
        const float2 hv = unpack2(u[q]);
        a[0].x = fmaf(x0, hv.x, a[0].x); a[0].y = fmaf(x0, hv.y, a[0].y);
        a[1].x = fmaf(x1, hv.x, a[1].x); a[1].y = fmaf(x1, hv.y, a[1].y);
        a[2].x = fmaf(x2, hv.x, a[2].x); a[2].y = fmaf(x2, hv.y, a[2].y);
        a[3].x = fmaf(x3, hv.x, a[3].x); a[3].y = fmaf(x3, hv.y, a[3].y);
        a[4].x = fmaf(x4, hv.x, a[4].x); a[4].y = fmaf(x4, hv.y, a[4].y);
    }
}

// ---------------------------------------------------------------------------
// Fused scatter + GEMM. Block = 512 threads (8 waves) = 16 nodes.
//
// Phase 1 (scatter): one node per wave, 2 nodes sequentially, scalar
//   e/dst/X metadata. NEW (round 10): software-pipelined one 8-edge
//   iteration ahead — next iteration's dst s_loads + gathers issue BEFORE
//   the current FMA block, so the forced lgkmcnt(0)/vmcnt waits overlap
//   the ~200cy FMA phase instead of serializing each iteration.
//
// Phase 2 (GEMM): out(16x128) = Rs(16x640) x Wt(128x640)^T + bias.
//   NEW (round 10): register-staged double-issue (T14 issue-early /
//   write-late). Chunk c+1's two global_load_dwordx4 issue before chunk
//   c's MFMA block; the ds_write lands after the read-barrier. Removes
//   the ~300cy exposed L2 latency per chunk of round 9 (which staged
//   load->wait->ds_write between two barriers). LDS footprint unchanged
//   (37.25 KB, 4 blocks/CU). Chunk-0 staging merges into the Rs barrier.
// ---------------------------------------------------------------------------
__global__ __launch_bounds__(512, 4) void fused_spectconv(
        const unsigned int* __restrict__ h2,   // (10000, 64) uint = 2 bf16 ch
        const float* __restrict__ X,           // (320000, 5)
        const int* __restrict__ dst,
        const int* __restrict__ offsets,
        const unsigned short* __restrict__ Wt, // (128, 640) bf16
        const float* __restrict__ bias,
        float* __restrict__ out) {
    __shared__ unsigned short Rs[16][648];     // 20.25 KB
    __shared__ unsigned short Bs[128][68];     // 17.0 KB  (total 37.25 KB)

    const int tid  = threadIdx.x;
    const int wv   = __builtin_amdgcn_readfirstlane(tid >> 6);   // scalar 0..7
    const int lane = tid & 63;
    const int m0   = blockIdx.x * 16;          // 625 blocks * 16 = 10000 exact

    for (int nn = 0; nn < 2; ++nn) {
        const int node = m0 + wv * 2 + nn;     // scalar
        const int e0 = offsets[node];          // s_load
        const int e1 = offsets[node + 1];      // s_load

        float2 a[5] = {{0.f,0.f},{0.f,0.f},{0.f,0.f},{0.f,0.f},{0.f,0.f}};

        int e = e0;
        int d[8]; unsigned int u[8];
        const bool have = (e + 7 < e1);
        if (have) {                            // prologue: first 8 in flight
#pragma unroll
            for (int q = 0; q < 8; ++q) d[q] = dst[e + q];        // s_loads
#pragma unroll
            for (int q = 0; q < 8; ++q)
                u[q] = h2[(size_t)d[q] * 64 + lane];              // gathers
        }
        for (; e + 15 < e1; e += 8) {          // pipelined steady state
            int dn[8]; unsigned int un[8];
#pragma unroll
            for (int q = 0; q < 8; ++q) dn[q] = dst[e + 8 + q];   // prefetch dst
#pragma unroll
            for (int q = 0; q < 8; ++q)
                un[q] = h2[(size_t)dn[q] * 64 + lane];            // prefetch gathers
            edge_fma8(X, e, u, a);             // consume current under latency
#pragma unroll
            for (int q = 0; q < 8; ++q) u[q] = un[q];
        }
        if (have) {                            // drain final prefetched block
            edge_fma8(X, e, u, a);
            e += 8;
        }
        for (; e < e1; ++e) {                  // scalar tail (<8 edges)
            const int dd = dst[e];
            const unsigned int uu = h2[(size_t)dd * 64 + lane];
            const float* Xp = X + (size_t)e * 5;
            const float x0 = Xp[0], x1 = Xp[1], x2 = Xp[2], x3 = Xp[3], x4 = Xp[4];
            const float2 hv = unpack2(uu);
            a[0].x = fmaf(x0, hv.x, a[0].x); a[0].y = fmaf(x0, hv.y, a[0].y);
            a[1].x = fmaf(x1, hv.x, a[1].x); a[1].y = fmaf(x1, hv.y, a[1].y);
            a[2].x = fmaf(x2, hv.x, a[2].x); a[2].y = fmaf(x2, hv.y, a[2].y);
            a[3].x = fmaf(x3, hv.x, a[3].x); a[3].y = fmaf(x3, hv.y, a[3].y);
            a[4].x = fmaf(x4, hv.x, a[4].x); a[4].y = fmaf(x4, hv.y, a[4].y);
        }

        // Rs row write: lane -> uint at [k*128 + 2*lane]; pitch 648 shorts
        // -> b128/b32 accesses tile all 32 banks at exactly 2-way (free).
        const int nrel = wv * 2 + nn;
        *(unsigned int*)&Rs[nrel][0 * 128 + 2 * lane] = pack2(a[0].x, a[0].y);
        *(unsigned int*)&Rs[nrel][1 * 128 + 2 * lane] = pack2(a[1].x, a[1].y);
        *(unsigned int*)&Rs[nrel][2 * 128 + 2 * lane] = pack2(a[2].x, a[2].y);
        *(unsigned int*)&Rs[nrel][3 * 128 + 2 * lane] = pack2(a[3].x, a[3].y);
        *(unsigned int*)&Rs[nrel][4 * 128 + 2 * lane] = pack2(a[4].x, a[4].y);
    }

    // ---- GEMM phase ----
    const int col  = lane & 15;
    const int quad = lane >> 4;
    const int c0   = wv * 16;

    // Staging geometry: 1024 x 16B per chunk, 2 per thread, coalesced
    // (8 consecutive threads = 128 B of one Wt row).
    const int srow = tid >> 3;                 // 0..63
    const int sseg = (tid & 7) * 8;            // short offset within 64-k chunk
    const unsigned short* wp0 = Wt + (size_t)srow * KDIM + sseg;
    const unsigned short* wp1 = wp0 + (size_t)64 * KDIM;

    // Chunk 0: stage before the Rs barrier (one barrier covers Rs + Bs0).
    {
        const short8 g0 = *(const short8*)wp0;
        const short8 g1 = *(const short8*)wp1;
        *(short8*)&Bs[srow][sseg]      = g0;
        *(short8*)&Bs[64 + srow][sseg] = g1;
    }
    __syncthreads();                           // Rs ready + Bs(0) ready

    floatx4 acc = {0.f, 0.f, 0.f, 0.f};

#pragma unroll
    for (int chunk = 0; chunk < 10; ++chunk) {
        short8 n0, n1;
        if (chunk < 9) {                       // issue next chunk's loads EARLY
            n0 = *(const short8*)(wp0 + (chunk + 1) * 64);
            n1 = *(const short8*)(wp1 + (chunk + 1) * 64);
        }
#pragma unroll
        for (int hh = 0; hh < 2; ++hh) {       // consume current chunk
            const short8 af = *(const short8*)&Rs[col][chunk * 64 + hh * 32 + quad * 8];
            const short8 bf = *(const short8*)&Bs[c0 + col][hh * 32 + quad * 8];
            acc = __builtin_amdgcn_mfma_f32_16x16x32_bf16(af, bf, acc, 0, 0, 0);
        }
        if (chunk < 9) {
            __syncthreads();                   // all waves done reading Bs(chunk)
            *(short8*)&Bs[srow][sseg]      = n0;   // vmcnt wait lands here,
            *(short8*)&Bs[64 + srow][sseg] = n1;   // ~hidden by MFMA phase
            __syncthreads();                   // Bs(chunk+1) ready
        }
    }

    const float bv = bias[c0 + col];
#pragma unroll
    for (int r = 0; r < 4; ++r) {
        const int m = m0 + quad * 4 + r;
        __builtin_nontemporal_store(acc[r] + bv, &out[(size_t)m * C_OUT + c0 + col]);
    }
}

// ---------------------------------------------------------------------------
extern "C" void kernel_launch(void* const* d_in, const int* in_sizes, int n_in,
                              void* d_out, int out_size, void* d_ws, size_t ws_size,
                              hipStream_t stream) {
    const float* h      = (const float*)d_in[0];   // (10000,128)
    const float* X      = (const float*)d_in[1];   // (320000,5)
    const int*   ei     = (const int*)d_in[2];     // (2,320000)
    const float* weight = (const float*)d_in[4];   // (5,128,128) == W(640,128)
    const float* bias   = (const float*)d_in[5];   // (128,)
    float* out = (float*)d_out;

    const int* src = ei;
    const int* dst = ei + N_EDGES;

    // Workspace: offsets [0,64KB) | hb bf16 [64KB, +2.56MB) | Wt bf16 [+4MB,..)
    char* wsb = (char*)d_ws;
    int*            offsets = (int*)wsb;
    uintx2*         hb4     = (uintx2*)(wsb + (64 << 10));
    unsigned short* Wtb     = (unsigned short*)(wsb + (64 << 10) + (4 << 20));

    prep<<<1370, 256, 0, stream>>>(h, hb4, weight, Wtb, src, offsets);
    fused_spectconv<<<625, 512, 0, stream>>>((const unsigned int*)hb4, X, dst,
                                             offsets, Wtb, bias, out);
}